// Round 3
// baseline (373.359 us; speedup 1.0000x reference)
//
#include <hip/hip_runtime.h>

#define Bb 8
#define Cc 8
#define Ff 257
#define Tt 1500
#define P2 750            // Tt/2 (float2 elements)
#define P4 375            // Tt/4 (float4 elements)
#define BF (Bb*Ff)        // 2056

__device__ __forceinline__ constexpr int odIdx(int c, int d) { return 7*c - c*(c-1)/2 + (d-c-1); } // c<d, 28 vals

constexpr float EPSv   = 1e-8f;
constexpr float PSDEPS = 1e-5f;
constexpr float IMADD  = 1e-5f + 1e-8f;   // +1j*PSD_EPS (inside _estimate_psd) +1j*eps (outside)

// async global->LDS, 16B per lane. LDS dest is wave-uniform base + lane*16 (HW).
__device__ __forceinline__ void gl2lds16(const float* g, float* l) {
    __builtin_amdgcn_global_load_lds((const __attribute__((address_space(1))) void*)g,
                                     (__attribute__((address_space(3))) void*)l, 16, 0, 0);
}

// ---------------- mask max, stage 1: partial max over F-chunks ----------------
__global__ void mask_pmax(const float* __restrict__ sm, const float* __restrict__ nm,
                          float* __restrict__ pmax_s, float* __restrict__ pmax_n) {
    int t  = blockIdx.x * 256 + threadIdx.x;
    int ch = blockIdx.y;
    int b  = blockIdx.z;
    if (t >= Tt) return;
    int f0 = ch * 33, f1 = min(Ff, f0 + 33);
    float ms = 0.f, mn = 0.f;
    for (int f = f0; f < f1; ++f) {
        ms = fmaxf(ms, fabsf(sm[(b*Ff + f)*Tt + t]));
        mn = fmaxf(mn, fabsf(nm[(b*Ff + f)*Tt + t]));
    }
    pmax_s[(b*8 + ch)*Tt + t] = ms;
    pmax_n[(b*8 + ch)*Tt + t] = mn;
}

// ---------------- mask max, stage 2: combine chunks -> 1/(max+eps) ----------------
__global__ void mask_inv(const float* __restrict__ pmax_s, const float* __restrict__ pmax_n,
                         float* __restrict__ inv_s, float* __restrict__ inv_n) {
    int t = blockIdx.x * 256 + threadIdx.x;
    int b = blockIdx.y;
    if (t >= Tt) return;
    float ms = 0.f, mn = 0.f;
    #pragma unroll
    for (int ch = 0; ch < 8; ++ch) {
        ms = fmaxf(ms, pmax_s[(b*8 + ch)*Tt + t]);
        mn = fmaxf(mn, pmax_n[(b*8 + ch)*Tt + t]);
    }
    inv_s[b*Tt + t] = 1.0f / (ms + EPSv);
    inv_n[b*Tt + t] = 1.0f / (mn + EPSv);
}

// ---------------- main fused kernel: one block (4 waves) per (b,f) ----------------
// Phase A is LDS-double-buffered: each iteration's 10 KB working set (8 cm_re +
// 8 cm_im + 2 mask + 2 inv segments of 512 B) is staged with async
// global_load_lds (size=16; one issue covers 2 consecutive segments via the
// lane<32 / lane>=32 source split), so VMEM latency never passes through VGPRs.
// Round 2 showed the allocator pins 64 VGPRs and serializes register-staged
// loads (135 us, VALUBusy 35%); ds_read latency (~100 cyc) is hidable even
// when chunked at 64 regs. Wave roles: (msel = wid>>1: speech/noise,
// part = wid&1: 28 off-diag re + diag c0..3 / 28 off-diag im + diag c4..7).
__global__ __launch_bounds__(256) __attribute__((amdgpu_waves_per_eu(4, 4)))
void mvdr_main(
    const float* __restrict__ smask, const float* __restrict__ nmask,
    const float* __restrict__ cmr,   const float* __restrict__ cmi,
    const float* __restrict__ inv_s, const float* __restrict__ inv_n,
    float* __restrict__ out)
{
    const int blk = blockIdx.x;
    const int b = blk / Ff, f = blk % Ff;
    const int tid  = threadIdx.x;
    const int wid  = tid >> 6;         // wave id [0,4)
    const int lane = tid & 63;
    const int msel = __builtin_amdgcn_readfirstlane(wid >> 1);   // 0: speech, 1: noise
    const int part = __builtin_amdgcn_readfirstlane(wid & 1);    // 0: re+diag_lo, 1: im+diag_hi

    // double-buffered stage tile: 20 segments x 128 floats per buffer
    __shared__ float tile0[20*128];
    __shared__ float tile1[20*128];

    // segment s -> global base pointer (per (b,f)):
    //  0..7: cmr ch c; 8..15: cmi ch c; 16: smask; 17: nmask; 18: inv_s; 19: inv_n
    auto segbase = [&](int s) -> const float* {
        if (s < 8)   return cmr + ((size_t)(b*Cc + s)      *Ff + f)*Tt;
        if (s < 16)  return cmi + ((size_t)(b*Cc + (s-8))  *Ff + f)*Tt;
        if (s == 16) return smask + ((size_t)b*Ff + f)*Tt;
        if (s == 17) return nmask + ((size_t)b*Ff + f)*Tt;
        if (s == 18) return inv_s + (size_t)b*Tt;
        return inv_n + (size_t)b*Tt;
    };
    // issue j covers segments (2j, 2j+1): lanes 0-31 read seg 2j, lanes 32-63 seg 2j+1
    auto pick = [&](int j) -> const float* {
        const float* e = segbase(2*j);
        const float* o = segbase(2*j + 1);
        return (lane & 32) ? o : e;
    };
    // wave w owns issues {w, w+4, w+8(<10)}: 10 issues/block/iter total
    const float* Pa  = pick(wid);
    const float* Pb  = pick(wid + 4);
    const bool  has3 = (wid < 2);
    const float* Pc  = has3 ? pick(wid + 8) : Pa;

    auto stage = [&](int it, float* dst) {
        int fi = it*128 + ((lane & 31) << 2);
        fi = min(fi, Tt - 4);                       // tail clamp: in-bounds duplicate
        gl2lds16(Pa + fi, dst + (2*wid)*128);
        gl2lds16(Pb + fi, dst + (2*(wid+4))*128);
        if (has3) gl2lds16(Pc + fi, dst + (2*(wid+8))*128);
    };

    // ---- Phase A: weighted covariance accumulation ----
    float acc[32];
    #pragma unroll
    for (int v = 0; v < 32; ++v) acc[v] = 0.f;
    float summ = 0.f;

    auto computeIter = [&](int it, const float* cur) {
        const float2* c2 = (const float2*)cur;
        float2 mk = c2[(16 + msel)*64 + lane];
        float2 iv = c2[(18 + msel)*64 + lane];
        float2 xr[8], xi[8];
        #pragma unroll
        for (int c = 0; c < 8; ++c) { xr[c] = c2[c*64 + lane]; xi[c] = c2[(8+c)*64 + lane]; }
        const float valid = (lane + it*64 < P2) ? 1.0f : 0.0f;
        float mx = mk.x * iv.x * valid, my = mk.y * iv.y * valid;
        if (part == 0) {
            summ += mx + my;
            #pragma unroll
            for (int c = 0; c < 8; ++c) {
                float ax = mx*xr[c].x, ay = my*xr[c].y, bx = mx*xi[c].x, by = my*xi[c].y;
                if (c < 4) {   // diag c in 0..3 (real)
                    float t0 = acc[28 + c];
                    t0 = fmaf(ax, xr[c].x, t0); t0 = fmaf(bx, xi[c].x, t0);
                    t0 = fmaf(ay, xr[c].y, t0); t0 = fmaf(by, xi[c].y, t0);
                    acc[28 + c] = t0;
                }
                #pragma unroll
                for (int d = c + 1; d < 8; ++d) {
                    const int k = odIdx(c, d);
                    float t0 = acc[k];
                    t0 = fmaf(ax, xr[d].x, t0); t0 = fmaf(bx, xi[d].x, t0);
                    t0 = fmaf(ay, xr[d].y, t0); t0 = fmaf(by, xi[d].y, t0);
                    acc[k] = t0;
                }
            }
        } else {
            #pragma unroll
            for (int c = 0; c < 8; ++c) {
                float ax = mx*xr[c].x, ay = my*xr[c].y, bx = mx*xi[c].x, by = my*xi[c].y;
                if (c >= 4) {  // diag c in 4..7 (real)
                    float t0 = acc[28 + (c - 4)];
                    t0 = fmaf(ax, xr[c].x, t0); t0 = fmaf(bx, xi[c].x, t0);
                    t0 = fmaf(ay, xr[c].y, t0); t0 = fmaf(by, xi[c].y, t0);
                    acc[28 + (c - 4)] = t0;
                }
                #pragma unroll
                for (int d = c + 1; d < 8; ++d) {
                    const int j = odIdx(c, d);
                    float t1 = acc[j];
                    t1 = fmaf(bx, xr[d].x, t1); t1 = fmaf(-ax, xi[d].x, t1);
                    t1 = fmaf(by, xr[d].y, t1); t1 = fmaf(-ay, xi[d].y, t1);
                    acc[j] = t1;
                }
            }
        }
    };

    stage(0, tile0);
    __syncthreads();                 // drains vmcnt -> tile0 ready
    #pragma unroll 1
    for (int it = 0; it < 12; it += 2) {
        stage(it + 1, tile1);        // prefetch next into other buffer
        computeIter(it, tile0);
        __syncthreads();             // drains vmcnt (tile1 ready) + reads of tile0 done
        if (it < 10) stage(it + 2, tile0);
        computeIter(it + 1, tile1);
        __syncthreads();
    }

    // ---- per-wave butterfly reduction + store to LDS ----
    __shared__ float OffRe[2][28], OffIm[2][28], Diagm[2][8];
    __shared__ float sumSN[2];

    #pragma unroll
    for (int o = 1; o <= 32; o <<= 1) {
        if (part == 0) summ += __shfl_xor(summ, o, 64);
        #pragma unroll
        for (int v = 0; v < 32; ++v) acc[v] += __shfl_xor(acc[v], o, 64);
    }
    if (lane == 0) {
        if (part == 0) {
            #pragma unroll
            for (int v = 0; v < 28; ++v) OffRe[msel][v] = acc[v];
            #pragma unroll
            for (int v = 0; v < 4; ++v) Diagm[msel][v] = acc[28 + v];
            sumSN[msel] = summ;
        } else {
            #pragma unroll
            for (int v = 0; v < 28; ++v) OffIm[msel][v] = acc[v];
            #pragma unroll
            for (int v = 0; v < 4; ++v) Diagm[msel][4 + v] = acc[28 + v];
        }
    }
    __syncthreads();

    // ---- build S matrix and augmented [N | I] in LDS (threads 0..63) ----
    __shared__ float SreM[64], SimM[64];
    __shared__ float Are[128], Aim[128];
    __shared__ float dre[8], dim_[8], wre[8], wim[8];

    if (tid < 64) {
        const float den_s = fmaxf(sumSN[0], PSDEPS);
        const float den_n = fmaxf(sumSN[1], PSDEPS);
        int cc_, dd_;
        float sv, nv;
        if (tid < 36) {
            int k = tid, c = 0; while (k >= 8 - c) { k -= 8 - c; ++c; } cc_ = c; dd_ = c + k;
            if (cc_ == dd_) { sv = Diagm[0][cc_] / den_s; nv = Diagm[1][cc_] / den_n; }
            else { int o = odIdx(cc_, dd_); sv = OffRe[0][o] / den_s; nv = OffRe[1][o] / den_n; }
        } else {
            int k = tid - 36, c = 0; while (k >= 7 - c) { k -= 7 - c; ++c; } cc_ = c; dd_ = c + k + 1;
            sv = OffIm[0][tid - 36] / den_s; nv = OffIm[1][tid - 36] / den_n;
        }
        if (tid < 36) {
            SreM[cc_*8 + dd_] = sv; SreM[dd_*8 + cc_] = sv;
            float nvd = nv + (cc_ == dd_ ? EPSv : 0.f);   // + eye*eps on noise diag
            Are[cc_*16 + dd_] = nvd; Are[dd_*16 + cc_] = nvd;
            if (cc_ == dd_) { SimM[cc_*8 + cc_] = IMADD; Aim[cc_*16 + cc_] = IMADD; }
        } else {
            SimM[cc_*8 + dd_] = IMADD + sv; SimM[dd_*8 + cc_] = IMADD - sv;
            Aim[cc_*16 + dd_] = IMADD + nv; Aim[dd_*16 + cc_] = IMADD - nv;
        }
        int r = tid >> 3, j = tid & 7;                    // identity right half
        Are[r*16 + 8 + j] = (r == j) ? 1.f : 0.f;
        Aim[r*16 + 8 + j] = 0.f;
    }
    __syncthreads();

    // ---- Gauss-Jordan inverse of N (unpivoted; N ~ HPD + tiny perturbation) ----
    {
        const bool act = tid < 64;
        const int r = (tid >> 3) & 7, cA = tid & 7;
        for (int k = 0; k < 8; ++k) {
            float pr = Are[k*16 + k], pi = Aim[k*16 + k];
            float idn = 1.0f / (pr*pr + pi*pi);
            float ipr = pr*idn, ipi = -pi*idn;
            if (act && r == k) {
                float ar0 = Are[k*16 + cA],     ai0 = Aim[k*16 + cA];
                Are[k*16 + cA]     = ar0*ipr - ai0*ipi; Aim[k*16 + cA]     = ar0*ipi + ai0*ipr;
                float ar1 = Are[k*16 + cA + 8], ai1 = Aim[k*16 + cA + 8];
                Are[k*16 + cA + 8] = ar1*ipr - ai1*ipi; Aim[k*16 + cA + 8] = ar1*ipi + ai1*ipr;
            }
            __syncthreads();
            float fr = Are[r*16 + k], fi = Aim[r*16 + k];
            float p0r = Are[k*16 + cA],     p0i = Aim[k*16 + cA];
            float p1r = Are[k*16 + cA + 8], p1i = Aim[k*16 + cA + 8];
            float o0r = 0.f, o0i = 0.f, o1r = 0.f, o1i = 0.f;
            if (r != k) {
                o0r = Are[r*16 + cA]     - (fr*p0r - fi*p0i);
                o0i = Aim[r*16 + cA]     - (fr*p0i + fi*p0r);
                o1r = Are[r*16 + cA + 8] - (fr*p1r - fi*p1i);
                o1i = Aim[r*16 + cA + 8] - (fr*p1i + fi*p1r);
            }
            __syncthreads();
            if (act && r != k) {
                Are[r*16 + cA]     = o0r; Aim[r*16 + cA]     = o0i;
                Are[r*16 + cA + 8] = o1r; Aim[r*16 + cA + 8] = o1i;
            }
            __syncthreads();
        }
    }

    // ---- u = inv@S e0, partial traces ----
    if (tid < 8) {
        int c = tid;
        float ur = 0.f, ui = 0.f, tr_r = 0.f, tr_i = 0.f;
        #pragma unroll
        for (int j = 0; j < 8; ++j) {
            float vr = Are[c*16 + 8 + j], vi = Aim[c*16 + 8 + j] + EPSv;  // inv + 1j*eps
            float s0r = SreM[j*8 + 0], s0i = SimM[j*8 + 0];
            ur += vr*s0r - vi*s0i; ui += vr*s0i + vi*s0r;
            float scr = SreM[j*8 + c], sci = SimM[j*8 + c];
            tr_r += vr*scr - vi*sci; tr_i += vr*sci + vi*scr;
        }
        dre[c] = tr_r; dim_[c] = tr_i;
        wre[c] = ur;   wim[c]  = ui;
    }
    __syncthreads();
    if (tid < 8) {
        float tr_r = EPSv, tr_i = 0.f;
        #pragma unroll
        for (int j = 0; j < 8; ++j) { tr_r += dre[j]; tr_i += dim_[j]; }
        float idn = 1.0f / (tr_r*tr_r + tr_i*tr_i);
        float ur = wre[tid], ui = wim[tid];
        wre[tid] = (ur*tr_r + ui*tr_i) * idn;     // w = u * conj(tr) / |tr|^2
        wim[tid] = (ui*tr_r - ur*tr_i) * idn;
    }
    __syncthreads();

    // ---- Phase B: out[b,f,t] = sum_c conj(w_c) * x_c(t), float4, 256 threads ----
    float wr[8], wi[8];
    #pragma unroll
    for (int c = 0; c < 8; ++c) { wr[c] = wre[c]; wi[c] = wim[c]; }

    const int cstride4 = Ff * P4;                       // float4 per (b,c) plane
    const float4* xr4 = (const float4*)(cmr + ((size_t)(b*Cc)*Ff + f)*Tt);
    const float4* xi4 = (const float4*)(cmi + ((size_t)(b*Cc)*Ff + f)*Tt);
    float4* outr4 = (float4*)out + (b*Ff + f)*P4;
    float4* outi4 = (float4*)out + (Bb*Ff)*P4 + (b*Ff + f)*P4;
    for (int pp = tid; pp < P4; pp += 256) {
        float rx = 0.f, ry = 0.f, rz = 0.f, rw = 0.f;
        float ix = 0.f, iy = 0.f, iz = 0.f, iw = 0.f;
        #pragma unroll
        for (int c = 0; c < 8; ++c) {
            float4 a  = xr4[pp + c*cstride4];
            float4 bb = xi4[pp + c*cstride4];
            rx = fmaf(wr[c], a.x, fmaf(wi[c], bb.x, rx));
            ry = fmaf(wr[c], a.y, fmaf(wi[c], bb.y, ry));
            rz = fmaf(wr[c], a.z, fmaf(wi[c], bb.z, rz));
            rw = fmaf(wr[c], a.w, fmaf(wi[c], bb.w, rw));
            ix = fmaf(wr[c], bb.x, fmaf(-wi[c], a.x, ix));
            iy = fmaf(wr[c], bb.y, fmaf(-wi[c], a.y, iy));
            iz = fmaf(wr[c], bb.z, fmaf(-wi[c], a.z, iz));
            iw = fmaf(wr[c], bb.w, fmaf(-wi[c], a.w, iw));
        }
        outr4[pp] = make_float4(rx, ry, rz, rw);
        outi4[pp] = make_float4(ix, iy, iz, iw);
    }
}

extern "C" void kernel_launch(void* const* d_in, const int* in_sizes, int n_in,
                              void* d_out, int out_size, void* d_ws, size_t ws_size,
                              hipStream_t stream) {
    const float* smask = (const float*)d_in[0];
    const float* nmask = (const float*)d_in[1];
    const float* cmr   = (const float*)d_in[2];
    const float* cmi   = (const float*)d_in[3];
    float* ws = (float*)d_ws;
    float* pmax_s = ws;                 // 8*8*1500 = 96000 floats
    float* pmax_n = ws + 96000;         // 96000
    float* inv_s  = ws + 192000;        // 12000
    float* inv_n  = ws + 204000;        // 12000  (total 864 KB)

    mask_pmax<<<dim3(6, 8, 8), 256, 0, stream>>>(smask, nmask, pmax_s, pmax_n);
    mask_inv <<<dim3(6, 8),    256, 0, stream>>>(pmax_s, pmax_n, inv_s, inv_n);
    mvdr_main<<<BF, 256, 0, stream>>>(smask, nmask, cmr, cmi, inv_s, inv_n, (float*)d_out);
}

// Round 4
// 301.659 us; speedup vs baseline: 1.2377x; 1.2377x over previous
//
#include <hip/hip_runtime.h>

#define Bb 8
#define Cc 8
#define Ff 257
#define Tt 1500
#define P2 750            // Tt/2 (float2 elements)
#define P4 375            // Tt/4 (float4 elements)
#define BF (Bb*Ff)        // 2056

// pair index within a 4-channel group, c<d in [0,4)
__device__ __forceinline__ constexpr int idx4(int c, int d) { return c*(7-c)/2 + d - c - 1; }

constexpr float EPSv   = 1e-8f;
constexpr float PSDEPS = 1e-5f;
constexpr float IMADD  = 1e-5f + 1e-8f;   // +1j*PSD_EPS (inside _estimate_psd) +1j*eps (outside)

// async global->LDS, 16B per lane. LDS dest is wave-uniform base + lane*16 (HW).
__device__ __forceinline__ void gl2lds16(const float* g, float* l) {
    __builtin_amdgcn_global_load_lds((const __attribute__((address_space(1))) void*)g,
                                     (__attribute__((address_space(3))) void*)l, 16, 0, 0);
}

// ---------------- mask max, stage 1: partial max over F-chunks ----------------
__global__ void mask_pmax(const float* __restrict__ sm, const float* __restrict__ nm,
                          float* __restrict__ pmax_s, float* __restrict__ pmax_n) {
    int t  = blockIdx.x * 256 + threadIdx.x;
    int ch = blockIdx.y;
    int b  = blockIdx.z;
    if (t >= Tt) return;
    int f0 = ch * 33, f1 = min(Ff, f0 + 33);
    float ms = 0.f, mn = 0.f;
    for (int f = f0; f < f1; ++f) {
        ms = fmaxf(ms, fabsf(sm[(b*Ff + f)*Tt + t]));
        mn = fmaxf(mn, fabsf(nm[(b*Ff + f)*Tt + t]));
    }
    pmax_s[(b*8 + ch)*Tt + t] = ms;
    pmax_n[(b*8 + ch)*Tt + t] = mn;
}

// ---------------- mask max, stage 2: combine chunks -> 1/(max+eps) ----------------
__global__ void mask_inv(const float* __restrict__ pmax_s, const float* __restrict__ pmax_n,
                         float* __restrict__ inv_s, float* __restrict__ inv_n) {
    int t = blockIdx.x * 256 + threadIdx.x;
    int b = blockIdx.y;
    if (t >= Tt) return;
    float ms = 0.f, mn = 0.f;
    #pragma unroll
    for (int ch = 0; ch < 8; ++ch) {
        ms = fmaxf(ms, pmax_s[(b*8 + ch)*Tt + t]);
        mn = fmaxf(mn, pmax_n[(b*8 + ch)*Tt + t]);
    }
    inv_s[b*Tt + t] = 1.0f / (ms + EPSv);
    inv_n[b*Tt + t] = 1.0f / (mn + EPSv);
}

// ---------------- main fused kernel: one block (8 waves) per (b,f) ----------------
// Rounds 1-3 evidence: backend pins this kernel at 64 VGPRs regardless of
// occupancy hints; 4-wave decomposition needs acc[32]+x[32] and spills.
// Fix: 8 waves (512 thr), quadrant split -> every wave holds <=16 acc and
// <=20 x-regs (~50 VGPR peak), honestly inside 64.
//   wave wid: msel = wid>>2 (0 speech / 1 noise), quad = wid&3:
//     quad0: channels 0-3 block  (4 diag re + 6 pairs re&im = 16 acc) + mask sum
//     quad1: channels 4-7 block  (16 acc)
//     quad2: lo x hi cross, real (16 acc)  [hi resident, lo streamed]
//     quad3: lo x hi cross, imag (16 acc)  [hi resident, lo streamed]
// Phase A staged via async global_load_lds into a 2x10KB LDS double buffer
// (structure verified in round 3); one __syncthreads per iteration drains
// vmcnt and protects the buffer swap. 64 VGPR + 23KB LDS -> 4 blocks/CU,
// 32 waves/CU (full occupancy) hides the 2-phase stage-drain stall.
__global__ __launch_bounds__(512)
void mvdr_main(
    const float* __restrict__ smask, const float* __restrict__ nmask,
    const float* __restrict__ cmr,   const float* __restrict__ cmi,
    const float* __restrict__ inv_s, const float* __restrict__ inv_n,
    float* __restrict__ out)
{
    const int blk = blockIdx.x;
    const int b = blk / Ff, f = blk % Ff;
    const int tid  = threadIdx.x;
    const int wid  = tid >> 6;         // wave id [0,8)
    const int lane = tid & 63;
    const int msel = __builtin_amdgcn_readfirstlane(wid >> 2);   // 0: speech, 1: noise
    const int quad = __builtin_amdgcn_readfirstlane(wid & 3);

    // double-buffered stage tile: 20 segments x 128 floats per buffer
    __shared__ float tile0[20*128];
    __shared__ float tile1[20*128];

    // segment s -> global base pointer (per (b,f)):
    //  0..7: cmr ch c; 8..15: cmi ch c; 16: smask; 17: nmask; 18: inv_s; 19: inv_n
    auto segbase = [&](int s) -> const float* {
        if (s < 8)   return cmr + ((size_t)(b*Cc + s)      *Ff + f)*Tt;
        if (s < 16)  return cmi + ((size_t)(b*Cc + (s-8))  *Ff + f)*Tt;
        if (s == 16) return smask + ((size_t)b*Ff + f)*Tt;
        if (s == 17) return nmask + ((size_t)b*Ff + f)*Tt;
        if (s == 18) return inv_s + (size_t)b*Tt;
        return inv_n + (size_t)b*Tt;
    };
    // issue j covers segments (2j, 2j+1): lanes 0-31 read seg 2j, lanes 32-63 seg 2j+1
    auto pick = [&](int j) -> const float* {
        const float* e = segbase(2*j);
        const float* o = segbase(2*j + 1);
        return (lane & 32) ? o : e;
    };
    // 10 issues/block/iter: wave w owns issue w; waves 0,1 also own issues 8,9
    const float* Pa   = pick(wid);
    const bool  has2  = (wid < 2);
    const float* Pb   = has2 ? pick(wid + 8) : Pa;

    auto stage = [&](int it, float* dst) {
        int fi = it*128 + ((lane & 31) << 2);
        fi = min(fi, Tt - 4);                       // tail clamp: in-bounds duplicate
        gl2lds16(Pa + fi, dst + wid*256);
        if (has2) gl2lds16(Pb + fi, dst + (wid + 8)*256);
    };

    // ---- Phase A: weighted covariance accumulation ----
    float acc[16];
    #pragma unroll
    for (int v = 0; v < 16; ++v) acc[v] = 0.f;
    float summ = 0.f;

    auto computeIter = [&](int it, const float* cur) {
        const float2* c2 = (const float2*)cur;
        float2 mk = c2[(16 + msel)*64 + lane];
        float2 iv = c2[(18 + msel)*64 + lane];
        const float valid = (lane + it*64 < P2) ? 1.0f : 0.0f;
        const float mx = mk.x * iv.x * valid, my = mk.y * iv.y * valid;

        if (quad <= 1) {
            // within-group block: channels c0..c0+3, diag(4) + 6 pairs re+im
            const int c0 = quad * 4;
            float2 xr[4], xi[4];
            #pragma unroll
            for (int j = 0; j < 4; ++j) {
                xr[j] = c2[(c0 + j)*64 + lane];
                xi[j] = c2[(8 + c0 + j)*64 + lane];
            }
            if (quad == 0) summ += mx + my;
            #pragma unroll
            for (int c = 0; c < 4; ++c) {
                float ax = mx*xr[c].x, ay = my*xr[c].y, bx = mx*xi[c].x, by = my*xi[c].y;
                {   // diag (real)
                    float t0 = acc[c];
                    t0 = fmaf(ax, xr[c].x, t0); t0 = fmaf(bx, xi[c].x, t0);
                    t0 = fmaf(ay, xr[c].y, t0); t0 = fmaf(by, xi[c].y, t0);
                    acc[c] = t0;
                }
                #pragma unroll
                for (int d = c + 1; d < 4; ++d) {
                    const int p = idx4(c, d);
                    float t0 = acc[4 + 2*p], t1 = acc[5 + 2*p];
                    t0 = fmaf(ax, xr[d].x, t0); t0 = fmaf(bx, xi[d].x, t0);
                    t0 = fmaf(ay, xr[d].y, t0); t0 = fmaf(by, xi[d].y, t0);
                    t1 = fmaf(bx, xr[d].x, t1); t1 = fmaf(-ax, xi[d].x, t1);
                    t1 = fmaf(by, xr[d].y, t1); t1 = fmaf(-ay, xi[d].y, t1);
                    acc[4 + 2*p] = t0; acc[5 + 2*p] = t1;
                }
            }
        } else {
            // cross lo x hi: hi channels resident, lo streamed one at a time
            float2 xrh[4], xih[4];
            #pragma unroll
            for (int j = 0; j < 4; ++j) {
                xrh[j] = c2[(4 + j)*64 + lane];
                xih[j] = c2[(12 + j)*64 + lane];
            }
            #pragma unroll
            for (int c = 0; c < 4; ++c) {
                float2 xrc = c2[c*64 + lane], xic = c2[(8 + c)*64 + lane];
                float ax = mx*xrc.x, ay = my*xrc.y, bx = mx*xic.x, by = my*xic.y;
                if (quad == 2) {
                    #pragma unroll
                    for (int d = 0; d < 4; ++d) {     // real part
                        float t0 = acc[c*4 + d];
                        t0 = fmaf(ax, xrh[d].x, t0); t0 = fmaf(bx, xih[d].x, t0);
                        t0 = fmaf(ay, xrh[d].y, t0); t0 = fmaf(by, xih[d].y, t0);
                        acc[c*4 + d] = t0;
                    }
                } else {
                    #pragma unroll
                    for (int d = 0; d < 4; ++d) {     // imag part
                        float t1 = acc[c*4 + d];
                        t1 = fmaf(bx, xrh[d].x, t1); t1 = fmaf(-ax, xih[d].x, t1);
                        t1 = fmaf(by, xrh[d].y, t1); t1 = fmaf(-ay, xih[d].y, t1);
                        acc[c*4 + d] = t1;
                    }
                }
            }
        }
    };

    stage(0, tile0);
    __syncthreads();                 // drains vmcnt -> tile0 ready
    #pragma unroll 1
    for (int it = 0; it < 12; it += 2) {
        stage(it + 1, tile1);        // prefetch next into other buffer
        computeIter(it, tile0);
        __syncthreads();             // tile1 staged + tile0 reads complete
        if (it < 10) stage(it + 2, tile0);
        computeIter(it + 1, tile1);
        __syncthreads();
    }

    // ---- per-wave butterfly reduction + store to LDS ----
    __shared__ float Racc[8][16];
    __shared__ float sumSN[2];

    #pragma unroll
    for (int o = 1; o <= 32; o <<= 1) {
        if (quad == 0) summ += __shfl_xor(summ, o, 64);
        #pragma unroll
        for (int v = 0; v < 16; ++v) acc[v] += __shfl_xor(acc[v], o, 64);
    }
    if (lane == 0) {
        #pragma unroll
        for (int v = 0; v < 16; ++v) Racc[wid][v] = acc[v];
        if (quad == 0) sumSN[msel] = summ;
    }
    __syncthreads();

    // ---- build S matrix and augmented [N | I] in LDS (threads 0..63) ----
    __shared__ float SreM[64], SimM[64];
    __shared__ float Are[128], Aim[128];
    __shared__ float dre[8], dim_[8], wre[8], wim[8];

    if (tid < 64) {
        const float den_s = fmaxf(sumSN[0], PSDEPS);
        const float den_n = fmaxf(sumSN[1], PSDEPS);
        int cc_, dd_, part;
        if (tid < 36) {
            int k = tid, c = 0; while (k >= 8 - c) { k -= 8 - c; ++c; } cc_ = c; dd_ = c + k;
            part = 0;
        } else {
            int k = tid - 36, c = 0; while (k >= 7 - c) { k -= 7 - c; ++c; } cc_ = c; dd_ = c + k + 1;
            part = 1;
        }
        // locate (cc_,dd_,part) in the quadrant layout
        int widx, idx;
        if (dd_ < 4)       { widx = 0; idx = (cc_ == dd_) ? cc_ : 4 + 2*idx4(cc_, dd_) + part; }
        else if (cc_ >= 4) { widx = 1; idx = (cc_ == dd_) ? cc_ - 4 : 4 + 2*idx4(cc_-4, dd_-4) + part; }
        else               { widx = 2 + part; idx = cc_*4 + (dd_ - 4); }
        float sv = Racc[widx][idx]     / den_s;
        float nv = Racc[4 + widx][idx] / den_n;
        if (tid < 36) {
            SreM[cc_*8 + dd_] = sv; SreM[dd_*8 + cc_] = sv;
            float nvd = nv + (cc_ == dd_ ? EPSv : 0.f);   // + eye*eps on noise diag
            Are[cc_*16 + dd_] = nvd; Are[dd_*16 + cc_] = nvd;
            if (cc_ == dd_) { SimM[cc_*8 + cc_] = IMADD; Aim[cc_*16 + cc_] = IMADD; }
        } else {
            SimM[cc_*8 + dd_] = IMADD + sv; SimM[dd_*8 + cc_] = IMADD - sv;
            Aim[cc_*16 + dd_] = IMADD + nv; Aim[dd_*16 + cc_] = IMADD - nv;
        }
        int r = tid >> 3, j = tid & 7;                    // identity right half
        Are[r*16 + 8 + j] = (r == j) ? 1.f : 0.f;
        Aim[r*16 + 8 + j] = 0.f;
    }
    __syncthreads();

    // ---- Gauss-Jordan inverse of N (unpivoted; N ~ HPD + tiny perturbation) ----
    {
        const bool act = tid < 64;
        const int r = (tid >> 3) & 7, cA = tid & 7;
        for (int k = 0; k < 8; ++k) {
            float pr = Are[k*16 + k], pi = Aim[k*16 + k];
            float idn = 1.0f / (pr*pr + pi*pi);
            float ipr = pr*idn, ipi = -pi*idn;
            if (act && r == k) {
                float ar0 = Are[k*16 + cA],     ai0 = Aim[k*16 + cA];
                Are[k*16 + cA]     = ar0*ipr - ai0*ipi; Aim[k*16 + cA]     = ar0*ipi + ai0*ipr;
                float ar1 = Are[k*16 + cA + 8], ai1 = Aim[k*16 + cA + 8];
                Are[k*16 + cA + 8] = ar1*ipr - ai1*ipi; Aim[k*16 + cA + 8] = ar1*ipi + ai1*ipr;
            }
            __syncthreads();
            float fr = Are[r*16 + k], fi = Aim[r*16 + k];
            float p0r = Are[k*16 + cA],     p0i = Aim[k*16 + cA];
            float p1r = Are[k*16 + cA + 8], p1i = Aim[k*16 + cA + 8];
            float o0r = 0.f, o0i = 0.f, o1r = 0.f, o1i = 0.f;
            if (r != k) {
                o0r = Are[r*16 + cA]     - (fr*p0r - fi*p0i);
                o0i = Aim[r*16 + cA]     - (fr*p0i + fi*p0r);
                o1r = Are[r*16 + cA + 8] - (fr*p1r - fi*p1i);
                o1i = Aim[r*16 + cA + 8] - (fr*p1i + fi*p1r);
            }
            __syncthreads();
            if (act && r != k) {
                Are[r*16 + cA]     = o0r; Aim[r*16 + cA]     = o0i;
                Are[r*16 + cA + 8] = o1r; Aim[r*16 + cA + 8] = o1i;
            }
            __syncthreads();
        }
    }

    // ---- u = inv@S e0, partial traces ----
    if (tid < 8) {
        int c = tid;
        float ur = 0.f, ui = 0.f, tr_r = 0.f, tr_i = 0.f;
        #pragma unroll
        for (int j = 0; j < 8; ++j) {
            float vr = Are[c*16 + 8 + j], vi = Aim[c*16 + 8 + j] + EPSv;  // inv + 1j*eps
            float s0r = SreM[j*8 + 0], s0i = SimM[j*8 + 0];
            ur += vr*s0r - vi*s0i; ui += vr*s0i + vi*s0r;
            float scr = SreM[j*8 + c], sci = SimM[j*8 + c];
            tr_r += vr*scr - vi*sci; tr_i += vr*sci + vi*scr;
        }
        dre[c] = tr_r; dim_[c] = tr_i;
        wre[c] = ur;   wim[c]  = ui;
    }
    __syncthreads();
    if (tid < 8) {
        float tr_r = EPSv, tr_i = 0.f;
        #pragma unroll
        for (int j = 0; j < 8; ++j) { tr_r += dre[j]; tr_i += dim_[j]; }
        float idn = 1.0f / (tr_r*tr_r + tr_i*tr_i);
        float ur = wre[tid], ui = wim[tid];
        wre[tid] = (ur*tr_r + ui*tr_i) * idn;     // w = u * conj(tr) / |tr|^2
        wim[tid] = (ui*tr_r - ur*tr_i) * idn;
    }
    __syncthreads();

    // ---- Phase B: out[b,f,t] = sum_c conj(w_c) * x_c(t), float4, 512 threads ----
    float wr[8], wi[8];
    #pragma unroll
    for (int c = 0; c < 8; ++c) { wr[c] = wre[c]; wi[c] = wim[c]; }

    const int cstride4 = Ff * P4;                       // float4 per (b,c) plane
    const float4* xr4 = (const float4*)(cmr + ((size_t)(b*Cc)*Ff + f)*Tt);
    const float4* xi4 = (const float4*)(cmi + ((size_t)(b*Cc)*Ff + f)*Tt);
    float4* outr4 = (float4*)out + (b*Ff + f)*P4;
    float4* outi4 = (float4*)out + (Bb*Ff)*P4 + (b*Ff + f)*P4;
    for (int pp = tid; pp < P4; pp += 512) {
        float rx = 0.f, ry = 0.f, rz = 0.f, rw = 0.f;
        float ix = 0.f, iy = 0.f, iz = 0.f, iw = 0.f;
        #pragma unroll
        for (int c = 0; c < 8; ++c) {
            float4 a  = xr4[pp + c*cstride4];
            float4 bb = xi4[pp + c*cstride4];
            rx = fmaf(wr[c], a.x, fmaf(wi[c], bb.x, rx));
            ry = fmaf(wr[c], a.y, fmaf(wi[c], bb.y, ry));
            rz = fmaf(wr[c], a.z, fmaf(wi[c], bb.z, rz));
            rw = fmaf(wr[c], a.w, fmaf(wi[c], bb.w, rw));
            ix = fmaf(wr[c], bb.x, fmaf(-wi[c], a.x, ix));
            iy = fmaf(wr[c], bb.y, fmaf(-wi[c], a.y, iy));
            iz = fmaf(wr[c], bb.z, fmaf(-wi[c], a.z, iz));
            iw = fmaf(wr[c], bb.w, fmaf(-wi[c], a.w, iw));
        }
        outr4[pp] = make_float4(rx, ry, rz, rw);
        outi4[pp] = make_float4(ix, iy, iz, iw);
    }
}

extern "C" void kernel_launch(void* const* d_in, const int* in_sizes, int n_in,
                              void* d_out, int out_size, void* d_ws, size_t ws_size,
                              hipStream_t stream) {
    const float* smask = (const float*)d_in[0];
    const float* nmask = (const float*)d_in[1];
    const float* cmr   = (const float*)d_in[2];
    const float* cmi   = (const float*)d_in[3];
    float* ws = (float*)d_ws;
    float* pmax_s = ws;                 // 8*8*1500 = 96000 floats
    float* pmax_n = ws + 96000;         // 96000
    float* inv_s  = ws + 192000;        // 12000
    float* inv_n  = ws + 204000;        // 12000  (total 864 KB)

    mask_pmax<<<dim3(6, 8, 8), 256, 0, stream>>>(smask, nmask, pmax_s, pmax_n);
    mask_inv <<<dim3(6, 8),    256, 0, stream>>>(pmax_s, pmax_n, inv_s, inv_n);
    mvdr_main<<<BF, 512, 0, stream>>>(smask, nmask, cmr, cmi, inv_s, inv_n, (float*)d_out);
}

// Round 5
// 300.028 us; speedup vs baseline: 1.2444x; 1.0054x over previous
//
#include <hip/hip_runtime.h>

#define Bb 8
#define Cc 8
#define Ff 257
#define Tt 1500
#define P2 750            // Tt/2 (float2 elements)
#define P4 375            // Tt/4 (float4 elements)
#define BF (Bb*Ff)        // 2056

// pair index within a 4-channel group, c<d in [0,4)
__device__ __forceinline__ constexpr int idx4(int c, int d) { return c*(7-c)/2 + d - c - 1; }

constexpr float EPSv   = 1e-8f;
constexpr float PSDEPS = 1e-5f;
constexpr float IMADD  = 1e-5f + 1e-8f;   // +1j*PSD_EPS (inside _estimate_psd) +1j*eps (outside)

// async global->LDS, 16B per lane. LDS dest is wave-uniform base + lane*16 (HW).
__device__ __forceinline__ void gl2lds16(const float* g, float* l) {
    __builtin_amdgcn_global_load_lds((const __attribute__((address_space(1))) void*)g,
                                     (__attribute__((address_space(3))) void*)l, 16, 0, 0);
}

// ---------------- mask max, stage 1: partial max over F-chunks ----------------
__global__ void mask_pmax(const float* __restrict__ sm, const float* __restrict__ nm,
                          float* __restrict__ pmax_s, float* __restrict__ pmax_n) {
    int t  = blockIdx.x * 256 + threadIdx.x;
    int ch = blockIdx.y;
    int b  = blockIdx.z;
    if (t >= Tt) return;
    int f0 = ch * 33, f1 = min(Ff, f0 + 33);
    float ms = 0.f, mn = 0.f;
    for (int f = f0; f < f1; ++f) {
        ms = fmaxf(ms, fabsf(sm[(b*Ff + f)*Tt + t]));
        mn = fmaxf(mn, fabsf(nm[(b*Ff + f)*Tt + t]));
    }
    pmax_s[(b*8 + ch)*Tt + t] = ms;
    pmax_n[(b*8 + ch)*Tt + t] = mn;
}

// ---------------- mask max, stage 2: combine chunks -> 1/(max+eps) ----------------
__global__ void mask_inv(const float* __restrict__ pmax_s, const float* __restrict__ pmax_n,
                         float* __restrict__ inv_s, float* __restrict__ inv_n) {
    int t = blockIdx.x * 256 + threadIdx.x;
    int b = blockIdx.y;
    if (t >= Tt) return;
    float ms = 0.f, mn = 0.f;
    #pragma unroll
    for (int ch = 0; ch < 8; ++ch) {
        ms = fmaxf(ms, pmax_s[(b*8 + ch)*Tt + t]);
        mn = fmaxf(mn, pmax_n[(b*8 + ch)*Tt + t]);
    }
    inv_s[b*Tt + t] = 1.0f / (ms + EPSv);
    inv_n[b*Tt + t] = 1.0f / (mn + EPSv);
}

// ---------------- main fused kernel: one block (8 waves) per (b,f) ----------------
// Quadrant decomposition (round 4, verified: 44 VGPR, no spill) + counted-vmcnt
// ring pipeline (this round). Round 4's __syncthreads drained vmcnt(0) every
// iteration -> ~900cyc HBM latency exposed 12x per block (24us/block wall).
// Now: 4-buffer LDS ring, 3 tiles in flight, raw s_barrier + per-wave
// s_waitcnt vmcnt(2L) (L = own gl2lds per stage). Loads stay in flight across
// barriers (T3/T4); tile k has ~3 iterations of slack before its wait.
// Overwrite safety: stage(k+3) -> buffer (k-1)&3; every wave passed barrier k
// only after finishing compute(k-1). Tail tiles 12-14 stage clamped (L1-hot
// single line) so the vmcnt immediate stays loop-invariant; final
// __syncthreads drains them.
__global__ __launch_bounds__(512)
void mvdr_main(
    const float* __restrict__ smask, const float* __restrict__ nmask,
    const float* __restrict__ cmr,   const float* __restrict__ cmi,
    const float* __restrict__ inv_s, const float* __restrict__ inv_n,
    float* __restrict__ out)
{
    const int blk = blockIdx.x;
    const int b = blk / Ff, f = blk % Ff;
    const int tid  = threadIdx.x;
    const int wid  = tid >> 6;         // wave id [0,8)
    const int lane = tid & 63;
    const int msel = __builtin_amdgcn_readfirstlane(wid >> 2);   // 0: speech, 1: noise
    const int quad = __builtin_amdgcn_readfirstlane(wid & 3);

    // ring of 4 stage tiles: 20 segments x 128 floats each (10 KB/tile)
    __shared__ float tiles[4][20*128];

    // segment s -> global base pointer (per (b,f)):
    //  0..7: cmr ch c; 8..15: cmi ch c; 16: smask; 17: nmask; 18: inv_s; 19: inv_n
    auto segbase = [&](int s) -> const float* {
        if (s < 8)   return cmr + ((size_t)(b*Cc + s)      *Ff + f)*Tt;
        if (s < 16)  return cmi + ((size_t)(b*Cc + (s-8))  *Ff + f)*Tt;
        if (s == 16) return smask + ((size_t)b*Ff + f)*Tt;
        if (s == 17) return nmask + ((size_t)b*Ff + f)*Tt;
        if (s == 18) return inv_s + (size_t)b*Tt;
        return inv_n + (size_t)b*Tt;
    };
    // issue j covers segments (2j, 2j+1): lanes 0-31 read seg 2j, lanes 32-63 seg 2j+1
    auto pick = [&](int j) -> const float* {
        const float* e = segbase(2*j);
        const float* o = segbase(2*j + 1);
        return (lane & 32) ? o : e;
    };
    // 10 issues/block/tile: wave w owns issue w; waves 0,1 also own issues 8,9
    const float* Pa   = pick(wid);
    const bool  has2  = (wid < 2);
    const float* Pb   = has2 ? pick(wid + 8) : Pa;

    auto stage = [&](int it, float* dst) {
        int fi = it*128 + ((lane & 31) << 2);
        fi = min(fi, Tt - 4);                       // tail clamp: in-bounds duplicate
        gl2lds16(Pa + fi, dst + wid*256);
        if (has2) gl2lds16(Pb + fi, dst + (wid + 8)*256);
    };

    // ---- Phase A: weighted covariance accumulation ----
    float acc[16];
    #pragma unroll
    for (int v = 0; v < 16; ++v) acc[v] = 0.f;
    float summ = 0.f;

    auto computeIter = [&](int it, const float* cur) {
        const float2* c2 = (const float2*)cur;
        float2 mk = c2[(16 + msel)*64 + lane];
        float2 iv = c2[(18 + msel)*64 + lane];
        const float valid = (lane + it*64 < P2) ? 1.0f : 0.0f;
        const float mx = mk.x * iv.x * valid, my = mk.y * iv.y * valid;

        if (quad <= 1) {
            // within-group block: channels c0..c0+3, diag(4) + 6 pairs re+im
            const int c0 = quad * 4;
            float2 xr[4], xi[4];
            #pragma unroll
            for (int j = 0; j < 4; ++j) {
                xr[j] = c2[(c0 + j)*64 + lane];
                xi[j] = c2[(8 + c0 + j)*64 + lane];
            }
            if (quad == 0) summ += mx + my;
            #pragma unroll
            for (int c = 0; c < 4; ++c) {
                float ax = mx*xr[c].x, ay = my*xr[c].y, bx = mx*xi[c].x, by = my*xi[c].y;
                {   // diag (real)
                    float t0 = acc[c];
                    t0 = fmaf(ax, xr[c].x, t0); t0 = fmaf(bx, xi[c].x, t0);
                    t0 = fmaf(ay, xr[c].y, t0); t0 = fmaf(by, xi[c].y, t0);
                    acc[c] = t0;
                }
                #pragma unroll
                for (int d = c + 1; d < 4; ++d) {
                    const int p = idx4(c, d);
                    float t0 = acc[4 + 2*p], t1 = acc[5 + 2*p];
                    t0 = fmaf(ax, xr[d].x, t0); t0 = fmaf(bx, xi[d].x, t0);
                    t0 = fmaf(ay, xr[d].y, t0); t0 = fmaf(by, xi[d].y, t0);
                    t1 = fmaf(bx, xr[d].x, t1); t1 = fmaf(-ax, xi[d].x, t1);
                    t1 = fmaf(by, xr[d].y, t1); t1 = fmaf(-ay, xi[d].y, t1);
                    acc[4 + 2*p] = t0; acc[5 + 2*p] = t1;
                }
            }
        } else {
            // cross lo x hi: hi channels resident, lo streamed one at a time
            float2 xrh[4], xih[4];
            #pragma unroll
            for (int j = 0; j < 4; ++j) {
                xrh[j] = c2[(4 + j)*64 + lane];
                xih[j] = c2[(12 + j)*64 + lane];
            }
            #pragma unroll
            for (int c = 0; c < 4; ++c) {
                float2 xrc = c2[c*64 + lane], xic = c2[(8 + c)*64 + lane];
                float ax = mx*xrc.x, ay = my*xrc.y, bx = mx*xic.x, by = my*xic.y;
                if (quad == 2) {
                    #pragma unroll
                    for (int d = 0; d < 4; ++d) {     // real part
                        float t0 = acc[c*4 + d];
                        t0 = fmaf(ax, xrh[d].x, t0); t0 = fmaf(bx, xih[d].x, t0);
                        t0 = fmaf(ay, xrh[d].y, t0); t0 = fmaf(by, xih[d].y, t0);
                        acc[c*4 + d] = t0;
                    }
                } else {
                    #pragma unroll
                    for (int d = 0; d < 4; ++d) {     // imag part
                        float t1 = acc[c*4 + d];
                        t1 = fmaf(bx, xrh[d].x, t1); t1 = fmaf(-ax, xih[d].x, t1);
                        t1 = fmaf(by, xrh[d].y, t1); t1 = fmaf(-ay, xih[d].y, t1);
                        acc[c*4 + d] = t1;
                    }
                }
            }
        }
    };

    // prologue: 3 tiles in flight
    stage(0, tiles[0]);
    stage(1, tiles[1]);
    stage(2, tiles[2]);
    #pragma unroll 1
    for (int k = 0; k < 12; ++k) {
        // wait for OWN tile-k loads (keep 2 newer tiles in flight), then sync.
        if (has2) asm volatile("s_waitcnt vmcnt(4)" ::: "memory");
        else      asm volatile("s_waitcnt vmcnt(2)" ::: "memory");
        __builtin_amdgcn_s_barrier();            // all waves' tile-k loads done
        __builtin_amdgcn_sched_barrier(0);       // pin: nothing moves above
        stage(k + 3, tiles[(k + 3) & 3]);        // overwrites buf (k-1)&3: safe past barrier k
        computeIter(k, tiles[k & 3]);
    }
    __syncthreads();                             // drain tail stages (tiles 12-14)

    // ---- per-wave butterfly reduction + store to LDS ----
    __shared__ float Racc[8][16];
    __shared__ float sumSN[2];

    #pragma unroll
    for (int o = 1; o <= 32; o <<= 1) {
        if (quad == 0) summ += __shfl_xor(summ, o, 64);
        #pragma unroll
        for (int v = 0; v < 16; ++v) acc[v] += __shfl_xor(acc[v], o, 64);
    }
    if (lane == 0) {
        #pragma unroll
        for (int v = 0; v < 16; ++v) Racc[wid][v] = acc[v];
        if (quad == 0) sumSN[msel] = summ;
    }
    __syncthreads();

    // ---- build S matrix and augmented [N | I] in LDS (threads 0..63) ----
    __shared__ float SreM[64], SimM[64];
    __shared__ float Are[128], Aim[128];
    __shared__ float dre[8], dim_[8], wre[8], wim[8];

    if (tid < 64) {
        const float den_s = fmaxf(sumSN[0], PSDEPS);
        const float den_n = fmaxf(sumSN[1], PSDEPS);
        int cc_, dd_, part;
        if (tid < 36) {
            int k = tid, c = 0; while (k >= 8 - c) { k -= 8 - c; ++c; } cc_ = c; dd_ = c + k;
            part = 0;
        } else {
            int k = tid - 36, c = 0; while (k >= 7 - c) { k -= 7 - c; ++c; } cc_ = c; dd_ = c + k + 1;
            part = 1;
        }
        // locate (cc_,dd_,part) in the quadrant layout
        int widx, idx;
        if (dd_ < 4)       { widx = 0; idx = (cc_ == dd_) ? cc_ : 4 + 2*idx4(cc_, dd_) + part; }
        else if (cc_ >= 4) { widx = 1; idx = (cc_ == dd_) ? cc_ - 4 : 4 + 2*idx4(cc_-4, dd_-4) + part; }
        else               { widx = 2 + part; idx = cc_*4 + (dd_ - 4); }
        float sv = Racc[widx][idx]     / den_s;
        float nv = Racc[4 + widx][idx] / den_n;
        if (tid < 36) {
            SreM[cc_*8 + dd_] = sv; SreM[dd_*8 + cc_] = sv;
            float nvd = nv + (cc_ == dd_ ? EPSv : 0.f);   // + eye*eps on noise diag
            Are[cc_*16 + dd_] = nvd; Are[dd_*16 + cc_] = nvd;
            if (cc_ == dd_) { SimM[cc_*8 + cc_] = IMADD; Aim[cc_*16 + cc_] = IMADD; }
        } else {
            SimM[cc_*8 + dd_] = IMADD + sv; SimM[dd_*8 + cc_] = IMADD - sv;
            Aim[cc_*16 + dd_] = IMADD + nv; Aim[dd_*16 + cc_] = IMADD - nv;
        }
        int r = tid >> 3, j = tid & 7;                    // identity right half
        Are[r*16 + 8 + j] = (r == j) ? 1.f : 0.f;
        Aim[r*16 + 8 + j] = 0.f;
    }
    __syncthreads();

    // ---- Gauss-Jordan inverse of N (unpivoted; N ~ HPD + tiny perturbation) ----
    {
        const bool act = tid < 64;
        const int r = (tid >> 3) & 7, cA = tid & 7;
        for (int k = 0; k < 8; ++k) {
            float pr = Are[k*16 + k], pi = Aim[k*16 + k];
            float idn = 1.0f / (pr*pr + pi*pi);
            float ipr = pr*idn, ipi = -pi*idn;
            if (act && r == k) {
                float ar0 = Are[k*16 + cA],     ai0 = Aim[k*16 + cA];
                Are[k*16 + cA]     = ar0*ipr - ai0*ipi; Aim[k*16 + cA]     = ar0*ipi + ai0*ipr;
                float ar1 = Are[k*16 + cA + 8], ai1 = Aim[k*16 + cA + 8];
                Are[k*16 + cA + 8] = ar1*ipr - ai1*ipi; Aim[k*16 + cA + 8] = ar1*ipi + ai1*ipr;
            }
            __syncthreads();
            float fr = Are[r*16 + k], fi = Aim[r*16 + k];
            float p0r = Are[k*16 + cA],     p0i = Aim[k*16 + cA];
            float p1r = Are[k*16 + cA + 8], p1i = Aim[k*16 + cA + 8];
            float o0r = 0.f, o0i = 0.f, o1r = 0.f, o1i = 0.f;
            if (r != k) {
                o0r = Are[r*16 + cA]     - (fr*p0r - fi*p0i);
                o0i = Aim[r*16 + cA]     - (fr*p0i + fi*p0r);
                o1r = Are[r*16 + cA + 8] - (fr*p1r - fi*p1i);
                o1i = Aim[r*16 + cA + 8] - (fr*p1i + fi*p1r);
            }
            __syncthreads();
            if (act && r != k) {
                Are[r*16 + cA]     = o0r; Aim[r*16 + cA]     = o0i;
                Are[r*16 + cA + 8] = o1r; Aim[r*16 + cA + 8] = o1i;
            }
            __syncthreads();
        }
    }

    // ---- u = inv@S e0, partial traces ----
    if (tid < 8) {
        int c = tid;
        float ur = 0.f, ui = 0.f, tr_r = 0.f, tr_i = 0.f;
        #pragma unroll
        for (int j = 0; j < 8; ++j) {
            float vr = Are[c*16 + 8 + j], vi = Aim[c*16 + 8 + j] + EPSv;  // inv + 1j*eps
            float s0r = SreM[j*8 + 0], s0i = SimM[j*8 + 0];
            ur += vr*s0r - vi*s0i; ui += vr*s0i + vi*s0r;
            float scr = SreM[j*8 + c], sci = SimM[j*8 + c];
            tr_r += vr*scr - vi*sci; tr_i += vr*sci + vi*scr;
        }
        dre[c] = tr_r; dim_[c] = tr_i;
        wre[c] = ur;   wim[c]  = ui;
    }
    __syncthreads();
    if (tid < 8) {
        float tr_r = EPSv, tr_i = 0.f;
        #pragma unroll
        for (int j = 0; j < 8; ++j) { tr_r += dre[j]; tr_i += dim_[j]; }
        float idn = 1.0f / (tr_r*tr_r + tr_i*tr_i);
        float ur = wre[tid], ui = wim[tid];
        wre[tid] = (ur*tr_r + ui*tr_i) * idn;     // w = u * conj(tr) / |tr|^2
        wim[tid] = (ui*tr_r - ur*tr_i) * idn;
    }
    __syncthreads();

    // ---- Phase B: out[b,f,t] = sum_c conj(w_c) * x_c(t), float4, 512 threads ----
    float wr[8], wi[8];
    #pragma unroll
    for (int c = 0; c < 8; ++c) { wr[c] = wre[c]; wi[c] = wim[c]; }

    const int cstride4 = Ff * P4;                       // float4 per (b,c) plane
    const float4* xr4 = (const float4*)(cmr + ((size_t)(b*Cc)*Ff + f)*Tt);
    const float4* xi4 = (const float4*)(cmi + ((size_t)(b*Cc)*Ff + f)*Tt);
    float4* outr4 = (float4*)out + (b*Ff + f)*P4;
    float4* outi4 = (float4*)out + (Bb*Ff)*P4 + (b*Ff + f)*P4;
    for (int pp = tid; pp < P4; pp += 512) {
        float rx = 0.f, ry = 0.f, rz = 0.f, rw = 0.f;
        float ix = 0.f, iy = 0.f, iz = 0.f, iw = 0.f;
        #pragma unroll
        for (int c = 0; c < 8; ++c) {
            float4 a  = xr4[pp + c*cstride4];
            float4 bb = xi4[pp + c*cstride4];
            rx = fmaf(wr[c], a.x, fmaf(wi[c], bb.x, rx));
            ry = fmaf(wr[c], a.y, fmaf(wi[c], bb.y, ry));
            rz = fmaf(wr[c], a.z, fmaf(wi[c], bb.z, rz));
            rw = fmaf(wr[c], a.w, fmaf(wi[c], bb.w, rw));
            ix = fmaf(wr[c], bb.x, fmaf(-wi[c], a.x, ix));
            iy = fmaf(wr[c], bb.y, fmaf(-wi[c], a.y, iy));
            iz = fmaf(wr[c], bb.z, fmaf(-wi[c], a.z, iz));
            iw = fmaf(wr[c], bb.w, fmaf(-wi[c], a.w, iw));
        }
        outr4[pp] = make_float4(rx, ry, rz, rw);
        outi4[pp] = make_float4(ix, iy, iz, iw);
    }
}

extern "C" void kernel_launch(void* const* d_in, const int* in_sizes, int n_in,
                              void* d_out, int out_size, void* d_ws, size_t ws_size,
                              hipStream_t stream) {
    const float* smask = (const float*)d_in[0];
    const float* nmask = (const float*)d_in[1];
    const float* cmr   = (const float*)d_in[2];
    const float* cmi   = (const float*)d_in[3];
    float* ws = (float*)d_ws;
    float* pmax_s = ws;                 // 8*8*1500 = 96000 floats
    float* pmax_n = ws + 96000;         // 96000
    float* inv_s  = ws + 192000;        // 12000
    float* inv_n  = ws + 204000;        // 12000  (total 864 KB)

    mask_pmax<<<dim3(6, 8, 8), 256, 0, stream>>>(smask, nmask, pmax_s, pmax_n);
    mask_inv <<<dim3(6, 8),    256, 0, stream>>>(pmax_s, pmax_n, inv_s, inv_n);
    mvdr_main<<<BF, 512, 0, stream>>>(smask, nmask, cmr, cmi, inv_s, inv_n, (float*)d_out);
}